// Round 1
// baseline (300.321 us; speedup 1.0000x reference)
//
#include <hip/hip_runtime.h>

#define N_NODES 50000
#define N_EDGES 800000
#define D_IN 256
#define D_OUT 64
#define NEG_SLOPE 0.2f

// ---------------------------------------------------------------------------
// GEMM: support[n][o] = sum_k x[n][k] * W[o][k] + b[o]
// One row per LANE. Each lane holds 64 f32 accumulators (one per output col).
// W is indexed with wave-uniform addresses -> compiler emits s_load; the FMA
// uses the SGPR as one operand. x row is read once via float4 (51.2 MB total).
// ---------------------------------------------------------------------------
__global__ __launch_bounds__(256) void gemm_rowlane(
    const float* __restrict__ x, const float* __restrict__ W,
    const float* __restrict__ b, float* __restrict__ support) {
  const int row = blockIdx.x * 256 + threadIdx.x;
  const int r = row < N_NODES ? row : N_NODES - 1;  // clamp: avoid OOB loads
  float acc[D_OUT];
#pragma unroll
  for (int o = 0; o < D_OUT; ++o) acc[o] = b[o];

  const float4* xrow = reinterpret_cast<const float4*>(x + (size_t)r * D_IN);
#pragma unroll 1   // keep code size ~one chunk; kc stays a real loop
  for (int kc = 0; kc < D_IN / 32; ++kc) {
    float xr[32];
#pragma unroll
    for (int q = 0; q < 8; ++q) {
      float4 v = xrow[kc * 8 + q];
      xr[q * 4 + 0] = v.x; xr[q * 4 + 1] = v.y;
      xr[q * 4 + 2] = v.z; xr[q * 4 + 3] = v.w;
    }
#pragma unroll
    for (int o = 0; o < D_OUT; ++o) {
      const float* wr = W + o * D_IN + kc * 32;  // wave-uniform -> s_load
#pragma unroll
      for (int k = 0; k < 32; ++k)
        acc[o] = fmaf(xr[k], wr[k], acc[o]);
    }
  }

  if (row < N_NODES) {
    float4* outr = reinterpret_cast<float4*>(support + (size_t)row * D_OUT);
#pragma unroll
    for (int q = 0; q < 16; ++q)
      outr[q] = make_float4(acc[q * 4 + 0], acc[q * 4 + 1],
                            acc[q * 4 + 2], acc[q * 4 + 3]);
  }
}

// ---------------------------------------------------------------------------
// Build CSR row_ptr from the SORTED edge_dst array. Each edge-thread writes
// the boundary entries it owns; gaps (nodes with zero edges) are filled by
// the boundary edge; head/tail handled by threads 0 and N_EDGES-1.
// ---------------------------------------------------------------------------
__global__ __launch_bounds__(256) void build_rowptr(
    const int* __restrict__ edge_dst, int* __restrict__ row_ptr) {
  const int e = blockIdx.x * 256 + threadIdx.x;
  if (e >= N_EDGES) return;
  const int d = edge_dst[e];
  if (e == 0) {
    for (int n = 0; n <= d; ++n) row_ptr[n] = 0;
  } else {
    const int dprev = edge_dst[e - 1];
    if (d != dprev)
      for (int n = dprev + 1; n <= d; ++n) row_ptr[n] = e;
  }
  if (e == N_EDGES - 1)
    for (int n = d + 1; n <= N_NODES; ++n) row_ptr[n] = N_EDGES;
}

// ---------------------------------------------------------------------------
// Aggregation + LeakyReLU: one wave per node. lane = output column.
// acc = sum over the node's contiguous edge range of val[e]*support[src[e]][lane].
// 4-way unroll (independent accumulators) to keep several gathers in flight.
// No atomics, no zero-init: every node's 64 outputs are written exactly once.
// ---------------------------------------------------------------------------
__global__ __launch_bounds__(256) void agg_kernel(
    const float* __restrict__ support, const int* __restrict__ edge_src,
    const float* __restrict__ edge_val, const int* __restrict__ row_ptr,
    float* __restrict__ out) {
  const int wid = (blockIdx.x * 256 + threadIdx.x) >> 6;
  const int lane = threadIdx.x & 63;
  if (wid >= N_NODES) return;
  const int lo = row_ptr[wid];       // wave-uniform s_load
  const int hi = row_ptr[wid + 1];

  float a0 = 0.f, a1 = 0.f, a2 = 0.f, a3 = 0.f;
  int e = lo;
  for (; e + 3 < hi; e += 4) {
    const int s0 = edge_src[e + 0], s1 = edge_src[e + 1];
    const int s2 = edge_src[e + 2], s3 = edge_src[e + 3];
    const float v0 = edge_val[e + 0], v1 = edge_val[e + 1];
    const float v2 = edge_val[e + 2], v3 = edge_val[e + 3];
    const float g0 = support[(size_t)s0 * D_OUT + lane];
    const float g1 = support[(size_t)s1 * D_OUT + lane];
    const float g2 = support[(size_t)s2 * D_OUT + lane];
    const float g3 = support[(size_t)s3 * D_OUT + lane];
    a0 = fmaf(v0, g0, a0);
    a1 = fmaf(v1, g1, a1);
    a2 = fmaf(v2, g2, a2);
    a3 = fmaf(v3, g3, a3);
  }
  for (; e < hi; ++e) {
    const int s = edge_src[e];
    const float v = edge_val[e];
    a0 = fmaf(v, support[(size_t)s * D_OUT + lane], a0);
  }
  const float acc = (a0 + a1) + (a2 + a3);
  out[(size_t)wid * D_OUT + lane] = acc >= 0.f ? acc : NEG_SLOPE * acc;
}

// ---------------------------------------------------------------------------
extern "C" void kernel_launch(void* const* d_in, const int* in_sizes, int n_in,
                              void* d_out, int out_size, void* d_ws, size_t ws_size,
                              hipStream_t stream) {
  const float* x        = (const float*)d_in[0];
  const float* W        = (const float*)d_in[1];
  const float* b        = (const float*)d_in[2];
  const int*   edge_src = (const int*)d_in[3];
  const int*   edge_dst = (const int*)d_in[4];
  const float* edge_val = (const float*)d_in[5];
  float* out = (float*)d_out;

  float* support = (float*)d_ws;                                   // 12.8 MB
  int* row_ptr = (int*)((char*)d_ws +
                        (size_t)N_NODES * D_OUT * sizeof(float));  // 200 KB

  hipLaunchKernelGGL(gemm_rowlane, dim3((N_NODES + 255) / 256), dim3(256), 0,
                     stream, x, W, b, support);
  hipLaunchKernelGGL(build_rowptr, dim3((N_EDGES + 255) / 256), dim3(256), 0,
                     stream, edge_dst, row_ptr);
  hipLaunchKernelGGL(agg_kernel, dim3((N_NODES * 64 + 255) / 256), dim3(256), 0,
                     stream, support, edge_src, edge_val, row_ptr, out);
}

// Round 2
// 138.564 us; speedup vs baseline: 2.1674x; 2.1674x over previous
//
#include <hip/hip_runtime.h>

#define N_NODES 50000
#define N_EDGES 800000
#define D_IN 256
#define D_OUT 64
#define NEG_SLOPE 0.2f

// ---------------------------------------------------------------------------
// GEMM: support[n][o] = sum_k x[n][k] * W[o][k] + b[o]
// Grid (196, 4): blockIdx.y picks a 16-col output block -> W indices are
// block-uniform -> s_load path (SGPR operand in v_fmac). Each thread owns one
// row and 16 outputs (4096 FMA). 784 blocks ~ 3 blocks/CU = 12 waves/CU,
// fixing the 9% occupancy / 13% VALUBusy latency stall of the 64-out version.
// x re-read 4x is absorbed by Infinity Cache (x = 51.2 MB < 256 MB).
// ---------------------------------------------------------------------------
__global__ __launch_bounds__(256) void gemm_split4(
    const float* __restrict__ x, const float* __restrict__ W,
    const float* __restrict__ b, float* __restrict__ support) {
  const int row = blockIdx.x * 256 + threadIdx.x;
  const int ob  = blockIdx.y;  // 16-column output block, block-uniform
  const int r = row < N_NODES ? row : N_NODES - 1;  // clamp: avoid OOB loads

  float acc[16];
#pragma unroll
  for (int j = 0; j < 16; ++j) acc[j] = b[ob * 16 + j];

  const float4* xrow = reinterpret_cast<const float4*>(x + (size_t)r * D_IN);
#pragma unroll 1  // kc stays a real loop; 512 FMA + 8 loads per iteration
  for (int kc = 0; kc < D_IN / 32; ++kc) {
    float xr[32];
#pragma unroll
    for (int q = 0; q < 8; ++q) {
      float4 v = xrow[kc * 8 + q];
      xr[q * 4 + 0] = v.x; xr[q * 4 + 1] = v.y;
      xr[q * 4 + 2] = v.z; xr[q * 4 + 3] = v.w;
    }
#pragma unroll
    for (int j = 0; j < 16; ++j) {
      const float* wr = W + (ob * 16 + j) * D_IN + kc * 32;  // uniform -> s_load
#pragma unroll
      for (int k = 0; k < 32; ++k)
        acc[j] = fmaf(xr[k], wr[k], acc[j]);
    }
  }

  if (row < N_NODES) {
    float4* outr =
        reinterpret_cast<float4*>(support + (size_t)row * D_OUT + ob * 16);
#pragma unroll
    for (int q = 0; q < 4; ++q)
      outr[q] = make_float4(acc[q * 4 + 0], acc[q * 4 + 1],
                            acc[q * 4 + 2], acc[q * 4 + 3]);
  }
}

// ---------------------------------------------------------------------------
// Build CSR row_ptr from the SORTED edge_dst array.
// ---------------------------------------------------------------------------
__global__ __launch_bounds__(256) void build_rowptr(
    const int* __restrict__ edge_dst, int* __restrict__ row_ptr) {
  const int e = blockIdx.x * 256 + threadIdx.x;
  if (e >= N_EDGES) return;
  const int d = edge_dst[e];
  if (e == 0) {
    for (int n = 0; n <= d; ++n) row_ptr[n] = 0;
  } else {
    const int dprev = edge_dst[e - 1];
    if (d != dprev)
      for (int n = dprev + 1; n <= d; ++n) row_ptr[n] = e;
  }
  if (e == N_EDGES - 1)
    for (int n = d + 1; n <= N_NODES; ++n) row_ptr[n] = N_EDGES;
}

// ---------------------------------------------------------------------------
// Aggregation + LeakyReLU: one wave per node, lane = output column.
// Gather support[src[e]][lane] is one contiguous 256B line per edge.
// ---------------------------------------------------------------------------
__global__ __launch_bounds__(256) void agg_kernel(
    const float* __restrict__ support, const int* __restrict__ edge_src,
    const float* __restrict__ edge_val, const int* __restrict__ row_ptr,
    float* __restrict__ out) {
  const int wid = (blockIdx.x * 256 + threadIdx.x) >> 6;
  const int lane = threadIdx.x & 63;
  if (wid >= N_NODES) return;
  const int lo = row_ptr[wid];
  const int hi = row_ptr[wid + 1];

  float a0 = 0.f, a1 = 0.f, a2 = 0.f, a3 = 0.f;
  int e = lo;
  for (; e + 3 < hi; e += 4) {
    const int s0 = edge_src[e + 0], s1 = edge_src[e + 1];
    const int s2 = edge_src[e + 2], s3 = edge_src[e + 3];
    const float v0 = edge_val[e + 0], v1 = edge_val[e + 1];
    const float v2 = edge_val[e + 2], v3 = edge_val[e + 3];
    const float g0 = support[(size_t)s0 * D_OUT + lane];
    const float g1 = support[(size_t)s1 * D_OUT + lane];
    const float g2 = support[(size_t)s2 * D_OUT + lane];
    const float g3 = support[(size_t)s3 * D_OUT + lane];
    a0 = fmaf(v0, g0, a0);
    a1 = fmaf(v1, g1, a1);
    a2 = fmaf(v2, g2, a2);
    a3 = fmaf(v3, g3, a3);
  }
  for (; e < hi; ++e) {
    const int s = edge_src[e];
    const float v = edge_val[e];
    a0 = fmaf(v, support[(size_t)s * D_OUT + lane], a0);
  }
  const float acc = (a0 + a1) + (a2 + a3);
  out[(size_t)wid * D_OUT + lane] = acc >= 0.f ? acc : NEG_SLOPE * acc;
}

// ---------------------------------------------------------------------------
extern "C" void kernel_launch(void* const* d_in, const int* in_sizes, int n_in,
                              void* d_out, int out_size, void* d_ws, size_t ws_size,
                              hipStream_t stream) {
  const float* x        = (const float*)d_in[0];
  const float* W        = (const float*)d_in[1];
  const float* b        = (const float*)d_in[2];
  const int*   edge_src = (const int*)d_in[3];
  const int*   edge_dst = (const int*)d_in[4];
  const float* edge_val = (const float*)d_in[5];
  float* out = (float*)d_out;

  float* support = (float*)d_ws;                                   // 12.8 MB
  int* row_ptr = (int*)((char*)d_ws +
                        (size_t)N_NODES * D_OUT * sizeof(float));  // 200 KB

  hipLaunchKernelGGL(gemm_split4, dim3((N_NODES + 255) / 256, 4), dim3(256), 0,
                     stream, x, W, b, support);
  hipLaunchKernelGGL(build_rowptr, dim3((N_EDGES + 255) / 256), dim3(256), 0,
                     stream, edge_dst, row_ptr);
  hipLaunchKernelGGL(agg_kernel, dim3((N_NODES * 64 + 255) / 256), dim3(256), 0,
                     stream, support, edge_src, edge_val, row_ptr, out);
}

// Round 3
// 70.838 us; speedup vs baseline: 4.2396x; 1.9561x over previous
//
#include <hip/hip_runtime.h>

#define N_NODES 50000
#define N_EDGES 800000
#define D_IN 256
#define D_OUT 64
#define NEG_SLOPE 0.2f

typedef __attribute__((ext_vector_type(8))) short bf16x8;   // 8 bf16 = 4 VGPR
typedef __attribute__((ext_vector_type(4))) float f32x4;    // MFMA C/D

__device__ inline ushort f2bf(float f) {  // f32 -> bf16 bits, round-nearest-even
  union { float f; unsigned u; } v; v.f = f;
  unsigned r = v.u + 0x7FFFu + ((v.u >> 16) & 1u);
  return (ushort)(r >> 16);
}
__device__ inline float bf2f(ushort h) {
  union { unsigned u; float f; } v; v.u = ((unsigned)h) << 16;
  return v.f;
}

// ---------------------------------------------------------------------------
// Prologue: W [64][256] f32 -> bf16 (N x K row-major), 64 KB -> 32 KB.
// ---------------------------------------------------------------------------
__global__ __launch_bounds__(256) void convert_w(
    const float* __restrict__ W, ushort* __restrict__ Wb) {
  const int i = blockIdx.x * 256 + threadIdx.x;
  if (i < D_OUT * D_IN) Wb[i] = f2bf(W[i]);
}

// ---------------------------------------------------------------------------
// MFMA GEMM: support[n][o] = sum_k x[n][k]*W[o][k] + b[o], stored as bf16.
// One wave computes a 16x64 tile via 4 n-blocks x 8 k-steps of
// mfma_f32_16x16x32_bf16. A is loaded straight from global x (f32) and
// converted in-register; B straight from bf16 Wb. Both operands use the SAME
// lane->k mapping (8 contiguous k per lane, k-group = lane>>4), so the
// hardware's internal k-permutation cancels. C/D layout (m89-verified):
// col = lane&15, row = (lane>>4)*4 + reg.
// ---------------------------------------------------------------------------
__global__ __launch_bounds__(256, 4) void gemm_mfma(
    const float* __restrict__ x, const ushort* __restrict__ Wb,
    const float* __restrict__ bias, ushort* __restrict__ support) {
  const int wave = threadIdx.x >> 6;
  const int lane = threadIdx.x & 63;
  const int m0 = blockIdx.x * 64 + wave * 16;   // this wave's 16 rows
  const int r16 = lane & 15;
  const int kg  = lane >> 4;                    // k-group 0..3

  int arow = m0 + r16;
  if (arow >= N_NODES) arow = N_NODES - 1;      // clamp (dup loads, stores guarded)
  const float*  xp = x  + (size_t)arow * D_IN + kg * 8;
  const ushort* wp = Wb + r16 * D_IN + kg * 8;

  f32x4 acc[4] = {f32x4{0.f,0.f,0.f,0.f}, f32x4{0.f,0.f,0.f,0.f},
                  f32x4{0.f,0.f,0.f,0.f}, f32x4{0.f,0.f,0.f,0.f}};

#pragma unroll
  for (int ks = 0; ks < D_IN / 32; ++ks) {
    const float4 xa = *reinterpret_cast<const float4*>(xp + ks * 32);
    const float4 xb = *reinterpret_cast<const float4*>(xp + ks * 32 + 4);
    bf16x8 a;
    a[0] = (short)f2bf(xa.x); a[1] = (short)f2bf(xa.y);
    a[2] = (short)f2bf(xa.z); a[3] = (short)f2bf(xa.w);
    a[4] = (short)f2bf(xb.x); a[5] = (short)f2bf(xb.y);
    a[6] = (short)f2bf(xb.z); a[7] = (short)f2bf(xb.w);
#pragma unroll
    for (int nb = 0; nb < 4; ++nb) {
      const bf16x8 bfrag =
          *reinterpret_cast<const bf16x8*>(wp + nb * 16 * D_IN + ks * 32);
      acc[nb] = __builtin_amdgcn_mfma_f32_16x16x32_bf16(a, bfrag, acc[nb], 0, 0, 0);
    }
  }

#pragma unroll
  for (int nb = 0; nb < 4; ++nb) {
    const int col = nb * 16 + r16;
    const float bv = bias[col];
#pragma unroll
    for (int i = 0; i < 4; ++i) {
      const int row = m0 + kg * 4 + i;          // C/D: row=(lane>>4)*4+reg
      if (row < N_NODES)
        support[(size_t)row * D_OUT + col] = f2bf(acc[nb][i] + bv);
    }
  }
}

// ---------------------------------------------------------------------------
// Build CSR row_ptr from the SORTED edge_dst array.
// ---------------------------------------------------------------------------
__global__ __launch_bounds__(256) void build_rowptr(
    const int* __restrict__ edge_dst, int* __restrict__ row_ptr) {
  const int e = blockIdx.x * 256 + threadIdx.x;
  if (e >= N_EDGES) return;
  const int d = edge_dst[e];
  if (e == 0) {
    for (int n = 0; n <= d; ++n) row_ptr[n] = 0;
  } else {
    const int dprev = edge_dst[e - 1];
    if (d != dprev)
      for (int n = dprev + 1; n <= d; ++n) row_ptr[n] = e;
  }
  if (e == N_EDGES - 1)
    for (int n = d + 1; n <= N_NODES; ++n) row_ptr[n] = N_EDGES;
}

// ---------------------------------------------------------------------------
// Aggregation + LeakyReLU: one wave per node, lane = output column.
// support is bf16 (2 B/lane gathers, 128 B per edge-row) -> half the logical
// gather traffic of f32. f32 accumulate, fused LeakyReLU, f32 out.
// ---------------------------------------------------------------------------
__global__ __launch_bounds__(256) void agg_kernel(
    const ushort* __restrict__ support, const int* __restrict__ edge_src,
    const float* __restrict__ edge_val, const int* __restrict__ row_ptr,
    float* __restrict__ out) {
  const int wid = (blockIdx.x * 256 + threadIdx.x) >> 6;
  const int lane = threadIdx.x & 63;
  if (wid >= N_NODES) return;
  const int lo = row_ptr[wid];
  const int hi = row_ptr[wid + 1];

  float a0 = 0.f, a1 = 0.f, a2 = 0.f, a3 = 0.f;
  int e = lo;
  for (; e + 3 < hi; e += 4) {
    const int s0 = edge_src[e + 0], s1 = edge_src[e + 1];
    const int s2 = edge_src[e + 2], s3 = edge_src[e + 3];
    const float v0 = edge_val[e + 0], v1 = edge_val[e + 1];
    const float v2 = edge_val[e + 2], v3 = edge_val[e + 3];
    const float g0 = bf2f(support[(size_t)s0 * D_OUT + lane]);
    const float g1 = bf2f(support[(size_t)s1 * D_OUT + lane]);
    const float g2 = bf2f(support[(size_t)s2 * D_OUT + lane]);
    const float g3 = bf2f(support[(size_t)s3 * D_OUT + lane]);
    a0 = fmaf(v0, g0, a0);
    a1 = fmaf(v1, g1, a1);
    a2 = fmaf(v2, g2, a2);
    a3 = fmaf(v3, g3, a3);
  }
  for (; e < hi; ++e) {
    const int s = edge_src[e];
    a0 = fmaf(edge_val[e], bf2f(support[(size_t)s * D_OUT + lane]), a0);
  }
  const float acc = (a0 + a1) + (a2 + a3);
  out[(size_t)wid * D_OUT + lane] = acc >= 0.f ? acc : NEG_SLOPE * acc;
}

// ---------------------------------------------------------------------------
extern "C" void kernel_launch(void* const* d_in, const int* in_sizes, int n_in,
                              void* d_out, int out_size, void* d_ws, size_t ws_size,
                              hipStream_t stream) {
  const float* x        = (const float*)d_in[0];
  const float* W        = (const float*)d_in[1];
  const float* b        = (const float*)d_in[2];
  const int*   edge_src = (const int*)d_in[3];
  const int*   edge_dst = (const int*)d_in[4];
  const float* edge_val = (const float*)d_in[5];
  float* out = (float*)d_out;

  // workspace layout
  ushort* support = (ushort*)d_ws;                                  // 6.4 MB
  char* p = (char*)d_ws + (size_t)N_NODES * D_OUT * sizeof(ushort);
  int* row_ptr = (int*)p;                                           // 200 KB
  p += (size_t)(N_NODES + 1) * sizeof(int);
  p = (char*)(((uintptr_t)p + 15) & ~(uintptr_t)15);
  ushort* Wb = (ushort*)p;                                          // 32 KB

  hipLaunchKernelGGL(convert_w, dim3((D_OUT * D_IN + 255) / 256), dim3(256), 0,
                     stream, W, Wb);
  hipLaunchKernelGGL(gemm_mfma, dim3((N_NODES + 63) / 64), dim3(256), 0,
                     stream, x, Wb, b, support);
  hipLaunchKernelGGL(build_rowptr, dim3((N_EDGES + 255) / 256), dim3(256), 0,
                     stream, edge_dst, row_ptr);
  hipLaunchKernelGGL(agg_kernel, dim3((N_NODES * 64 + 255) / 256), dim3(256), 0,
                     stream, support, edge_src, edge_val, row_ptr, out);
}

// Round 4
// 62.774 us; speedup vs baseline: 4.7842x; 1.1285x over previous
//
#include <hip/hip_runtime.h>

#define N_NODES 50000
#define N_EDGES 800000
#define D_IN 256
#define D_OUT 64
#define NEG_SLOPE 0.2f

typedef __attribute__((ext_vector_type(8))) short bf16x8;   // 8 bf16 = 4 VGPR
typedef __attribute__((ext_vector_type(4))) float f32x4;    // MFMA C/D

__device__ inline ushort f2bf(float f) {  // f32 -> bf16 bits, round-nearest-even
  union { float f; unsigned u; } v; v.f = f;
  unsigned r = v.u + 0x7FFFu + ((v.u >> 16) & 1u);
  return (ushort)(r >> 16);
}
__device__ inline float bf2f(ushort h) {
  union { unsigned u; float f; } v; v.u = ((unsigned)h) << 16;
  return v.f;
}

// ---------------------------------------------------------------------------
// Prep (fused): W f32->bf16 (blocks 0..63) + CSR row_ptr from sorted edge_dst.
// ---------------------------------------------------------------------------
__global__ __launch_bounds__(256) void prep_kernel(
    const float* __restrict__ W, ushort* __restrict__ Wb,
    const int* __restrict__ edge_dst, int* __restrict__ row_ptr) {
  const int i = blockIdx.x * 256 + threadIdx.x;
  if (i < D_OUT * D_IN) Wb[i] = f2bf(W[i]);

  const int e = i;
  if (e >= N_EDGES) return;
  const int d = edge_dst[e];
  if (e == 0) {
    for (int n = 0; n <= d; ++n) row_ptr[n] = 0;
  } else {
    const int dprev = edge_dst[e - 1];
    if (d != dprev)
      for (int n = dprev + 1; n <= d; ++n) row_ptr[n] = e;
  }
  if (e == N_EDGES - 1)
    for (int n = d + 1; n <= N_NODES; ++n) row_ptr[n] = N_EDGES;
}

// ---------------------------------------------------------------------------
// MFMA GEMM: support[n][o] = sum_k x[n][k]*W[o][k] + b[o], stored as bf16.
// One wave = 16x64 tile, 4 n-blocks x 8 k-steps of mfma_f32_16x16x32_bf16.
// A straight from global x (f32->bf16 in-register); B from bf16 Wb (L1-hot).
// Same lane->k mapping on both operands so internal k-permutation cancels.
// C/D layout (m89-verified): col = lane&15, row = (lane>>4)*4 + reg.
// (256,8): ~45 VGPR -> 8 waves/SIMD legal; doubles x-latency hiding.
// ---------------------------------------------------------------------------
__global__ __launch_bounds__(256, 8) void gemm_mfma(
    const float* __restrict__ x, const ushort* __restrict__ Wb,
    const float* __restrict__ bias, ushort* __restrict__ support) {
  const int wave = threadIdx.x >> 6;
  const int lane = threadIdx.x & 63;
  const int m0 = blockIdx.x * 64 + wave * 16;   // this wave's 16 rows
  const int r16 = lane & 15;
  const int kg  = lane >> 4;                    // k-group 0..3

  int arow = m0 + r16;
  if (arow >= N_NODES) arow = N_NODES - 1;      // clamp (dup loads, stores guarded)
  const float*  xp = x  + (size_t)arow * D_IN + kg * 8;
  const ushort* wp = Wb + r16 * D_IN + kg * 8;

  f32x4 acc[4] = {f32x4{0.f,0.f,0.f,0.f}, f32x4{0.f,0.f,0.f,0.f},
                  f32x4{0.f,0.f,0.f,0.f}, f32x4{0.f,0.f,0.f,0.f}};

#pragma unroll
  for (int ks = 0; ks < D_IN / 32; ++ks) {
    const float4 xa = *reinterpret_cast<const float4*>(xp + ks * 32);
    const float4 xb = *reinterpret_cast<const float4*>(xp + ks * 32 + 4);
    bf16x8 a;
    a[0] = (short)f2bf(xa.x); a[1] = (short)f2bf(xa.y);
    a[2] = (short)f2bf(xa.z); a[3] = (short)f2bf(xa.w);
    a[4] = (short)f2bf(xb.x); a[5] = (short)f2bf(xb.y);
    a[6] = (short)f2bf(xb.z); a[7] = (short)f2bf(xb.w);
#pragma unroll
    for (int nb = 0; nb < 4; ++nb) {
      const bf16x8 bfrag =
          *reinterpret_cast<const bf16x8*>(wp + nb * 16 * D_IN + ks * 32);
      acc[nb] = __builtin_amdgcn_mfma_f32_16x16x32_bf16(a, bfrag, acc[nb], 0, 0, 0);
    }
  }

#pragma unroll
  for (int nb = 0; nb < 4; ++nb) {
    const int col = nb * 16 + r16;
    const float bv = bias[col];
#pragma unroll
    for (int i = 0; i < 4; ++i) {
      const int row = m0 + kg * 4 + i;          // C/D: row=(lane>>4)*4+reg
      if (row < N_NODES)
        support[(size_t)row * D_OUT + col] = f2bf(acc[nb][i] + bv);
    }
  }
}

// ---------------------------------------------------------------------------
// Aggregation + LeakyReLU: one wave per node, lane = output column.
// 8 independent accumulators keep 8 gathers (one 128B line each) in flight;
// mean degree = 16 -> ~2 main-loop iterations per node. (256,8) doubles
// resident waves for gather-latency hiding.
// ---------------------------------------------------------------------------
__global__ __launch_bounds__(256, 8) void agg_kernel(
    const ushort* __restrict__ support, const int* __restrict__ edge_src,
    const float* __restrict__ edge_val, const int* __restrict__ row_ptr,
    float* __restrict__ out) {
  const int wid = (blockIdx.x * 256 + threadIdx.x) >> 6;
  const int lane = threadIdx.x & 63;
  if (wid >= N_NODES) return;
  const int lo = row_ptr[wid];
  const int hi = row_ptr[wid + 1];

  float a[8];
#pragma unroll
  for (int q = 0; q < 8; ++q) a[q] = 0.f;

  int e = lo;
  for (; e + 7 < hi; e += 8) {
    int   s[8];
    float v[8];
#pragma unroll
    for (int q = 0; q < 8; ++q) { s[q] = edge_src[e + q]; v[q] = edge_val[e + q]; }
#pragma unroll
    for (int q = 0; q < 8; ++q)
      a[q] = fmaf(v[q], bf2f(support[(size_t)s[q] * D_OUT + lane]), a[q]);
  }
  if (e + 3 < hi) {
    int   s[4];
    float v[4];
#pragma unroll
    for (int q = 0; q < 4; ++q) { s[q] = edge_src[e + q]; v[q] = edge_val[e + q]; }
#pragma unroll
    for (int q = 0; q < 4; ++q)
      a[q] = fmaf(v[q], bf2f(support[(size_t)s[q] * D_OUT + lane]), a[q]);
    e += 4;
  }
  for (; e < hi; ++e)
    a[0] = fmaf(edge_val[e], bf2f(support[(size_t)edge_src[e] * D_OUT + lane]), a[0]);

  const float acc = ((a[0] + a[1]) + (a[2] + a[3])) + ((a[4] + a[5]) + (a[6] + a[7]));
  out[(size_t)wid * D_OUT + lane] = acc >= 0.f ? acc : NEG_SLOPE * acc;
}

// ---------------------------------------------------------------------------
extern "C" void kernel_launch(void* const* d_in, const int* in_sizes, int n_in,
                              void* d_out, int out_size, void* d_ws, size_t ws_size,
                              hipStream_t stream) {
  const float* x        = (const float*)d_in[0];
  const float* W        = (const float*)d_in[1];
  const float* b        = (const float*)d_in[2];
  const int*   edge_src = (const int*)d_in[3];
  const int*   edge_dst = (const int*)d_in[4];
  const float* edge_val = (const float*)d_in[5];
  float* out = (float*)d_out;

  // workspace layout
  ushort* support = (ushort*)d_ws;                                  // 6.4 MB
  char* p = (char*)d_ws + (size_t)N_NODES * D_OUT * sizeof(ushort);
  int* row_ptr = (int*)p;                                           // 200 KB
  p += (size_t)(N_NODES + 1) * sizeof(int);
  p = (char*)(((uintptr_t)p + 15) & ~(uintptr_t)15);
  ushort* Wb = (ushort*)p;                                          // 32 KB

  hipLaunchKernelGGL(prep_kernel, dim3((N_EDGES + 255) / 256), dim3(256), 0,
                     stream, W, Wb, edge_dst, row_ptr);
  hipLaunchKernelGGL(gemm_mfma, dim3((N_NODES + 63) / 64), dim3(256), 0,
                     stream, x, Wb, b, support);
  hipLaunchKernelGGL(agg_kernel, dim3((N_NODES * 64 + 255) / 256), dim3(256), 0,
                     stream, support, edge_src, edge_val, row_ptr, out);
}